// Round 2
// baseline (640.298 us; speedup 1.0000x reference)
//
#include <hip/hip_runtime.h>

#define THRESH 0.1f

// Input: 96 planes (32*3) of 1024x1024 fp32.
// Each wave (64 lanes) processes a strip of 16 horizontally adjacent 16x16 blocks
// (16 rows x 256 cols). Lane l owns 4 consecutive image columns (one float4 per
// row, 16 rows = 64 VGPRs of data).
//
// Row-WHT stages: m=1,2 are inside the lane's float4 (pure register ops);
// m=4,8 are lane^1 / lane^2 -> __shfl_xor with masks 1,2 (DPP quad_perm, no LDS).
__global__ __launch_bounds__(256) void wht16_kernel(const float* __restrict__ in,
                                                    float* __restrict__ out) {
    const int wave = (blockIdx.x << 2) + (threadIdx.x >> 6);
    const int lane = threadIdx.x & 63;
    // wave -> p (plane 0..95), i (block-row 0..63), s (quarter-row 0..3)
    const int s = wave & 3;
    const int i = (wave >> 2) & 63;
    const int p = wave >> 8;

    const float* src = in + (size_t)p * 1048576 + (size_t)(i * 16) * 1024
                          + s * 256 + lane * 4;

    float v[16][4];
#pragma unroll
    for (int r = 0; r < 16; ++r) {
        const float4 t = *reinterpret_cast<const float4*>(src + (size_t)r * 1024);
        v[r][0] = t.x; v[r][1] = t.y; v[r][2] = t.z; v[r][3] = t.w;
    }

    // ---- column WHT (along r), in-register butterflies ----
#pragma unroll
    for (int m = 1; m < 16; m <<= 1) {
#pragma unroll
        for (int r = 0; r < 16; ++r) {
            if (!(r & m)) {
#pragma unroll
                for (int k = 0; k < 4; ++k) {
                    const float a = v[r][k];
                    const float b = v[r | m][k];
                    v[r][k]     = a + b;
                    v[r | m][k] = a - b;
                }
            }
        }
    }

    // ---- row WHT stages m=1,2: within the lane's 4 columns ----
#pragma unroll
    for (int r = 0; r < 16; ++r) {
        float a, b;
        a = v[r][0]; b = v[r][1]; v[r][0] = a + b; v[r][1] = a - b;
        a = v[r][2]; b = v[r][3]; v[r][2] = a + b; v[r][3] = a - b;
        a = v[r][0]; b = v[r][2]; v[r][0] = a + b; v[r][2] = a - b;
        a = v[r][1]; b = v[r][3]; v[r][1] = a + b; v[r][3] = a - b;
    }

    // ---- row WHT stages m=4 (lane^1), m=8 (lane^2): DPP shuffles + sign-FMA ----
    const float s1 = (lane & 1) ? -1.0f : 1.0f;
    const float s2 = (lane & 2) ? -1.0f : 1.0f;
#pragma unroll
    for (int r = 0; r < 16; ++r) {
#pragma unroll
        for (int k = 0; k < 4; ++k) {
            const float pa = __shfl_xor(v[r][k], 1, 64);
            v[r][k] = fmaf(s1, v[r][k], pa);   // lower: v+pa, upper: pa-v
        }
    }
#pragma unroll
    for (int r = 0; r < 16; ++r) {
#pragma unroll
        for (int k = 0; k < 4; ++k) {
            const float pa = __shfl_xor(v[r][k], 2, 64);
            v[r][k] = fmaf(s2, v[r][k], pa);
        }
    }

    // ---- scale (1/16), threshold, vectorized store into blocked layout ----
    // out[plane][i][j][r][cc]; lane covers block j = s*16 + lane/4, cols (lane&3)*4..+3
    const int j = (s << 4) + (lane >> 2);
    float4* dst = reinterpret_cast<float4*>(out)
                + ((size_t)((p * 64 + i) * 64 + j) << 6) + (lane & 3);
#pragma unroll
    for (int r = 0; r < 16; ++r) {
        float4 o;
        float x;
        x = v[r][0] * 0.0625f; o.x = (fabsf(x) < THRESH) ? 0.0f : x;
        x = v[r][1] * 0.0625f; o.y = (fabsf(x) < THRESH) ? 0.0f : x;
        x = v[r][2] * 0.0625f; o.z = (fabsf(x) < THRESH) ? 0.0f : x;
        x = v[r][3] * 0.0625f; o.w = (fabsf(x) < THRESH) ? 0.0f : x;
        dst[r * 4] = o;   // 16B store, offsets fold into 13-bit immediates
    }
}

extern "C" void kernel_launch(void* const* d_in, const int* in_sizes, int n_in,
                              void* d_out, int out_size, void* d_ws, size_t ws_size,
                              hipStream_t stream) {
    const float* in = (const float*)d_in[0];
    float* out = (float*)d_out;
    // 96 planes * 64 block-rows * 4 quarter-strips = 24576 waves; 4 waves/block
    const int blocks = 6144;
    wht16_kernel<<<blocks, 256, 0, stream>>>(in, out);
}

// Round 3
// 636.675 us; speedup vs baseline: 1.0057x; 1.0057x over previous
//
#include <hip/hip_runtime.h>

#define THRESH 0.1f

// Input: 96 planes (32*3) of 1024x1024 fp32. 16x16 block 2D WHT + threshold.
//
// Each wave (64 lanes) processes 8 horizontally adjacent 16x16 blocks
// (16 rows x 128 cols = 8 KB). Lane l owns: block b = l>>3, col group
// cg = l&3 (4 consecutive cols), row parity par = (l>>2)&1 (8 rows of one
// parity) -> 8 float4 = 32 data VGPRs.
//
// Per load instruction: 2 contiguous 512 B segments (rows 2q, 2q+1).
// Per store instruction: 8 contiguous 128 B full-line segments.
// Column-WHT: stage m=1 cross-lane (xor 4), m=2,4,8 in-register (q bits).
// Row-WHT: m=1,2 in-register (k bits), m=4,8 cross-lane (xor 1, xor 2 = DPP).
__global__ __launch_bounds__(256) void wht16_kernel(const float* __restrict__ in,
                                                    float* __restrict__ out) {
    const int wave = (blockIdx.x << 2) + (threadIdx.x >> 6);
    const int lane = threadIdx.x & 63;

    const int s8 = wave & 7;          // strip of 8 blocks within the row
    const int i  = (wave >> 3) & 63;  // block row
    const int p  = wave >> 9;         // plane 0..95

    const int b   = lane >> 3;        // block within strip 0..7
    const int par = (lane >> 2) & 1;  // row parity
    const int cg  = lane & 3;         // col group 0..3

    const float* src = in + (size_t)p * 1048576
                     + (size_t)(i * 16 + par) * 1024
                     + s8 * 128 + b * 16 + cg * 4;

    float v[8][4];
#pragma unroll
    for (int q = 0; q < 8; ++q) {
        const float4 t = *reinterpret_cast<const float4*>(src + (size_t)q * 2048);
        v[q][0] = t.x; v[q][1] = t.y; v[q][2] = t.z; v[q][3] = t.w;
    }

    // ---- column WHT, stage m=1 (row bit0 = par -> lane bit 2) ----
    const float sp = par ? -1.0f : 1.0f;
#pragma unroll
    for (int q = 0; q < 8; ++q)
#pragma unroll
        for (int k = 0; k < 4; ++k) {
            const float pa = __shfl_xor(v[q][k], 4, 64);
            v[q][k] = fmaf(sp, v[q][k], pa);   // par=0: v+pa, par=1: pa-v
        }

    // ---- column WHT, stages m=2,4,8 -> in-register butterflies on q bits ----
#pragma unroll
    for (int mm = 1; mm < 8; mm <<= 1) {
#pragma unroll
        for (int q = 0; q < 8; ++q) {
            if (!(q & mm)) {
#pragma unroll
                for (int k = 0; k < 4; ++k) {
                    const float a = v[q][k];
                    const float c = v[q | mm][k];
                    v[q][k]      = a + c;
                    v[q | mm][k] = a - c;
                }
            }
        }
    }

    // ---- row WHT, stages m=1,2: within the lane's 4 columns ----
#pragma unroll
    for (int q = 0; q < 8; ++q) {
        float a, c;
        a = v[q][0]; c = v[q][1]; v[q][0] = a + c; v[q][1] = a - c;
        a = v[q][2]; c = v[q][3]; v[q][2] = a + c; v[q][3] = a - c;
        a = v[q][0]; c = v[q][2]; v[q][0] = a + c; v[q][2] = a - c;
        a = v[q][1]; c = v[q][3]; v[q][1] = a + c; v[q][3] = a - c;
    }

    // ---- row WHT, stages m=4 (lane^1), m=8 (lane^2): DPP quad-perm ----
    const float s1 = (lane & 1) ? -1.0f : 1.0f;
    const float s2 = (lane & 2) ? -1.0f : 1.0f;
#pragma unroll
    for (int q = 0; q < 8; ++q)
#pragma unroll
        for (int k = 0; k < 4; ++k) {
            const float pa = __shfl_xor(v[q][k], 1, 64);
            v[q][k] = fmaf(s1, v[q][k], pa);
        }
#pragma unroll
    for (int q = 0; q < 8; ++q)
#pragma unroll
        for (int k = 0; k < 4; ++k) {
            const float pa = __shfl_xor(v[q][k], 2, 64);
            v[q][k] = fmaf(s2, v[q][k], pa);
        }

    // ---- scale (1/16), threshold, store: 8 x 128B full-line segments/inst ----
    const int j = s8 * 8 + b;
    float* dst = out + ((size_t)((p * 64 + i) * 64 + j) << 8)
               + par * 16 + cg * 4;
#pragma unroll
    for (int q = 0; q < 8; ++q) {
        float4 o;
        float x;
        x = v[q][0] * 0.0625f; o.x = (fabsf(x) < THRESH) ? 0.0f : x;
        x = v[q][1] * 0.0625f; o.y = (fabsf(x) < THRESH) ? 0.0f : x;
        x = v[q][2] * 0.0625f; o.z = (fabsf(x) < THRESH) ? 0.0f : x;
        x = v[q][3] * 0.0625f; o.w = (fabsf(x) < THRESH) ? 0.0f : x;
        *reinterpret_cast<float4*>(dst + q * 32) = o;   // (2q+par)*16 + cg*4
    }
}

extern "C" void kernel_launch(void* const* d_in, const int* in_sizes, int n_in,
                              void* d_out, int out_size, void* d_ws, size_t ws_size,
                              hipStream_t stream) {
    const float* in = (const float*)d_in[0];
    float* out = (float*)d_out;
    // each wave handles 2048 elements (8 blocks); 4 waves per workgroup
    const long long n = (long long)in_sizes[0];
    const int blocks = (int)(n / 8192);   // 12288
    wht16_kernel<<<blocks, 256, 0, stream>>>(in, out);
}